// Round 10
// baseline (210.387 us; speedup 1.0000x reference)
//
#include <hip/hip_runtime.h>
#include <hip/hip_bf16.h>

#define HIDDEN 128
#define NRAD 6

typedef short bf16x8 __attribute__((ext_vector_type(8)));
typedef float f32x4 __attribute__((ext_vector_type(4)));

__device__ __forceinline__ float swishf(float z) {
    return z / (1.0f + __expf(-z));
}

__device__ __forceinline__ unsigned short f2bf(float f) {
    unsigned int u = __float_as_uint(f);
    unsigned int r = (u + 0x7FFFu + ((u >> 16) & 1u)) >> 16;
    return (unsigned short)r;
}

__device__ __forceinline__ float bf2f(unsigned int s) {
    return __uint_as_float(s << 16);
}

__device__ __forceinline__ unsigned int pk2bf(float x, float y) {
    __hip_bfloat162 h = __float22bfloat162_rn(make_float2(x, y));
    return *reinterpret_cast<unsigned int*>(&h);
}

// ---------------------------------------------------------------------------
// Kernel 1: T1 = emb_table @ W1 + b (bias folded), T3 = emb_table @ W3
// ---------------------------------------------------------------------------
__global__ void k_emb_proj(const float* __restrict__ emb, const float* __restrict__ W,
                           const float* __restrict__ bvec,
                           float* __restrict__ T1, float* __restrict__ T3,
                           float* __restrict__ out_scalar) {
    int v = blockIdx.x;
    int h = threadIdx.x;
    if (v == 0 && h == 0) *out_scalar = 1.0f;
    const float* er = emb + v * HIDDEN;
    float a1 = bvec[h], a3 = 0.f;
    #pragma unroll 4
    for (int k = 0; k < HIDDEN; ++k) {
        float e = er[k];
        a1 += e * W[k * HIDDEN + h];
        a3 += e * W[(256 + k) * HIDDEN + h];
    }
    T1[v * HIDDEN + h] = a1;
    T3[v * HIDDEN + h] = a3;
}

// ---------------------------------------------------------------------------
// Kernel 1b: repack weights into bf16 MFMA fragments.
//  - w2f/w4f: standard k-order W^T A-operand fragments (consumed by k_node).
//  - w5f: pi-PERMUTED k-order: slot s=g*8+j of k-tile kt holds row
//         h = 32*kt + 16*(j>>2) + 4*g + (j&3) (matches phase-1 MFMA output).
//  - wrbf: phase-1 A-operand table (slot 6 = bias, slot 7 = 0).
// ---------------------------------------------------------------------------
__global__ void k_wprep(const float* __restrict__ W,
                        const float* __restrict__ W_rbf, const float* __restrict__ b_rbf,
                        short* __restrict__ wf, short* __restrict__ wrbf) {
    int gid = blockIdx.x * 256 + threadIdx.x;
    if (gid < 4096) {                       // w2f, w4f (standard order)
        int m = gid >> 11;
        int t = gid & 2047;
        int l = t & 63;
        int tile = t >> 6;
        int n = tile >> 2, kt = tile & 3;
        int k0 = kt * 32 + (l >> 4) * 8;
        int col = n * 16 + (l & 15);
        const float* Wm = W + (m == 0 ? 128 : 384) * HIDDEN;
        bf16x8 v;
        #pragma unroll
        for (int j = 0; j < 8; ++j) v[j] = (short)f2bf(Wm[(k0 + j) * HIDDEN + col]);
        *(bf16x8*)(wf + (size_t)gid * 8) = v;
    } else if (gid < 6144) {                // w5f (pi-permuted k order)
        int t = gid - 4096;
        int l = t & 63;
        int tile = t >> 6;
        int n = tile >> 2, kt = tile & 3;
        int g = l >> 4;
        int col = n * 16 + (l & 15);
        const float* W5 = W + 512 * HIDDEN;
        bf16x8 v;
        #pragma unroll
        for (int j = 0; j < 8; ++j) {
            int hk = 32 * kt + 16 * (j >> 2) + 4 * g + (j & 3);
            v[j] = (short)f2bf(W5[hk * HIDDEN + col]);
        }
        *(bf16x8*)(wf + (size_t)gid * 8) = v;
    } else if (gid < 6272) {                // wrbf table (2 KB)
        int t2 = gid - 6144;                // 0..127
        int n = t2 >> 4, e = t2 & 15;
        int hp = n * 16 + e;
        bf16x8 v;
        #pragma unroll
        for (int j = 0; j < 8; ++j) {
            float val = (j < NRAD) ? W_rbf[j * HIDDEN + hp]
                      : (j == 6 ? b_rbf[hp] : 0.f);
            v[j] = (short)f2bf(val);
        }
        *(bf16x8*)(wrbf + (size_t)t2 * 8) = v;
    }
}

// ---------------------------------------------------------------------------
// Kernel 2 (MFMA): A[n] = T1[x[n]] + chi[n]@W2 ; B[n] = T3[x[n]] + chi[n]@W4
// LDS-FREE: lane (er,g) loads its chi fragment directly from global
// (32 contiguous bytes; 4 lanes/row cover a full 128-B line -> coalesced).
// Abf/Bbf stored H-PERMUTED (pos g*32+n*4+j holds h=n*16+g*4+j).
// ---------------------------------------------------------------------------
#define NB 64
__global__ __launch_bounds__(256) void k_node(const int* __restrict__ x,
        const float* __restrict__ chi,
        const short* __restrict__ w2f, const short* __restrict__ w4f,
        const float* __restrict__ T1, const float* __restrict__ T3,
        short* __restrict__ Abf, short* __restrict__ Bbf, int n_nodes) {
    int t = threadIdx.x;
    int l = t & 63;
    int wv = t >> 6;
    int er = l & 15;
    int g = l >> 4;
    int n0 = blockIdx.x * NB;

    int gn = n0 + wv * 16 + er;
    bool live = (gn < n_nodes);
    int ndc = live ? gn : (n_nodes - 1);

    int xv = x[ndc];

    // chi fragments: direct global loads + cvt (identical values to old path)
    bf16x8 cfrag[4];
    const float* crow = chi + (size_t)ndc * HIDDEN + g * 8;
    #pragma unroll
    for (int kt = 0; kt < 4; ++kt) {
        float4 c0 = *(const float4*)(crow + kt * 32);
        float4 c1 = *(const float4*)(crow + kt * 32 + 4);
        union { bf16x8 v; unsigned int u[4]; } cu;
        cu.u[0] = pk2bf(c0.x, c0.y);
        cu.u[1] = pk2bf(c0.z, c0.w);
        cu.u[2] = pk2bf(c1.x, c1.y);
        cu.u[3] = pk2bf(c1.z, c1.w);
        cfrag[kt] = cu.v;
    }

    int hq = g * 4;
    short* arow = Abf + (size_t)gn * HIDDEN + g * 32;
    short* brow = Bbf + (size_t)gn * HIDDEN + g * 32;

    #pragma unroll
    for (int np = 0; np < 4; ++np) {
        uint4 oa, ob;
        #pragma unroll
        for (int half = 0; half < 2; ++half) {
            int n = 2 * np + half;
            f32x4 aA = {0.f, 0.f, 0.f, 0.f};
            f32x4 aB = {0.f, 0.f, 0.f, 0.f};
            #pragma unroll
            for (int kt = 0; kt < 4; ++kt) {
                bf16x8 w2 = *(const bf16x8*)(w2f + ((size_t)(n * 4 + kt) * 64 + l) * 8);
                bf16x8 w4 = *(const bf16x8*)(w4f + ((size_t)(n * 4 + kt) * 64 + l) * 8);
                aA = __builtin_amdgcn_mfma_f32_16x16x32_bf16(w2, cfrag[kt], aA, 0, 0, 0);
                aB = __builtin_amdgcn_mfma_f32_16x16x32_bf16(w4, cfrag[kt], aB, 0, 0, 0);
            }
            if (live) {
                int h = n * 16 + hq;
                float4 t1 = *(const float4*)(T1 + (size_t)xv * HIDDEN + h);
                float4 t3 = *(const float4*)(T3 + (size_t)xv * HIDDEN + h);
                unsigned int a0 = pk2bf(aA[0] + t1.x, aA[1] + t1.y);
                unsigned int a1 = pk2bf(aA[2] + t1.z, aA[3] + t1.w);
                unsigned int b0 = pk2bf(aB[0] + t3.x, aB[1] + t3.y);
                unsigned int b1 = pk2bf(aB[2] + t3.z, aB[3] + t3.w);
                if (half == 0) { oa.x = a0; oa.y = a1; ob.x = b0; ob.y = b1; }
                else           { oa.z = a0; oa.w = a1; ob.z = b0; ob.w = b1; }
            }
        }
        if (live) {
            *(uint4*)(arow + np * 8) = oa;
            *(uint4*)(brow + np * 8) = ob;
        }
    }
}

// ---------------------------------------------------------------------------
// Kernel 3: 64 edges/block, 4 waves, 2 barriers. Phase-1 is an MFMA
// (K=6 padded to 32; slot 6 = 1.0 carries the bias); w5f pi-permuted so
// pfrag assembly is lane-local. LDS arena (36096 B, 4 blocks/CU):
//   [0, 32768)      w5_s -- dead after MFMAs, reused as seg after barrier2
//   [32768, 34816)  wrbf_s
//   [34816, 35584)  rbf_b (64 x 6 bf16)
//   [35584, 36096)  i_s, j_s
// ---------------------------------------------------------------------------
#define EB 64
__global__ __launch_bounds__(256) void k_edge(const float* __restrict__ rbf,
        const int* __restrict__ ei, const int* __restrict__ ej,
        const short* __restrict__ w5f, const short* __restrict__ wrbf,
        const short* __restrict__ Abf, const short* __restrict__ Bbf,
        float* __restrict__ out, int n_edges) {
    __shared__ uint4 smem4[36096 / 16];
    char* base = (char*)smem4;
    short* w5_s   = (short*)base;
    short* wrbf_s = (short*)(base + 32768);
    unsigned short* rbf_b = (unsigned short*)(base + 34816);
    int*   i_s    = (int*)(base + 35584);
    int*   j_s    = (int*)(base + 35840);

    int e0 = blockIdx.x * EB;
    int t = threadIdx.x;
    int l = t & 63;
    int wv = t >> 6;
    int g = l >> 4;
    int er = l & 15;

    #pragma unroll
    for (int it = 0; it < 8; ++it) {
        int q = t + it * 256;
        ((uint4*)w5_s)[q] = ((const uint4*)w5f)[q];
    }
    if (t < 128) ((uint4*)wrbf_s)[t] = ((const uint4*)wrbf)[t];
    #pragma unroll
    for (int it = 0; it < 2; ++it) {
        int q = t + it * 256;
        if (q < EB * NRAD) {
            int gidx = e0 * NRAD + q;
            rbf_b[q] = (gidx < n_edges * NRAD) ? f2bf(rbf[gidx]) : (unsigned short)0;
        } else if (q < EB * NRAD + EB) {
            int e = q - EB * NRAD;
            int ge = e0 + e;
            i_s[e] = (ge < n_edges) ? ei[ge] : 0;
        } else {
            int e = q - EB * NRAD - EB;
            int ge = e0 + e;
            j_s[e] = (ge < n_edges) ? ej[ge] : 0;
        }
    }
    __syncthreads();   // barrier 1

    int e_loc = wv * 16 + er;
    const short* ap = Abf + (size_t)i_s[e_loc] * HIDDEN + g * 32;
    const short* bp = Bbf + (size_t)j_s[e_loc] * HIDDEN + g * 32;
    uint4 avq[4], bvq[4];
    #pragma unroll
    for (int q = 0; q < 4; ++q) {
        avq[q] = *(const uint4*)(ap + q * 8);
        bvq[q] = *(const uint4*)(bp + q * 8);
    }

    union { bf16x8 v; unsigned int u[4]; } rbfrag;
    {
        const char* rp = (const char*)rbf_b + e_loc * 12;
        unsigned int q0 = *(const unsigned int*)(rp);
        unsigned int q1 = *(const unsigned int*)(rp + 4);
        unsigned int q2 = *(const unsigned int*)(rp + 8);
        bool g0 = (g == 0);
        rbfrag.u[0] = g0 ? q0 : 0u;
        rbfrag.u[1] = g0 ? q1 : 0u;
        rbfrag.u[2] = g0 ? q2 : 0u;
        rbfrag.u[3] = g0 ? 0x00003F80u : 0u;   // slot6 = 1.0 (bias), slot7 = 0
    }
    f32x4 accp[8];
    #pragma unroll
    for (int n = 0; n < 8; ++n) {
        bf16x8 wa = *(const bf16x8*)(wrbf_s + (n * 16 + er) * 8);
        f32x4 z = {0.f, 0.f, 0.f, 0.f};
        accp[n] = __builtin_amdgcn_mfma_f32_16x16x32_bf16(wa, rbfrag.v, z, 0, 0, 0);
    }
    unsigned int word0[8], word1[8];
    #pragma unroll
    for (int n = 0; n < 8; ++n) {
        word0[n] = pk2bf(swishf(accp[n][0]), swishf(accp[n][1]));
        word1[n] = pk2bf(swishf(accp[n][2]), swishf(accp[n][3]));
    }
    bf16x8 pfrag[4];
    #pragma unroll
    for (int kt = 0; kt < 4; ++kt) {
        union { bf16x8 v; unsigned int u[4]; } pu;
        pu.u[0] = word0[2 * kt];
        pu.u[1] = word1[2 * kt];
        pu.u[2] = word0[2 * kt + 1];
        pu.u[3] = word1[2 * kt + 1];
        pfrag[kt] = pu.v;
    }

    f32x4 acc[8];
    #pragma unroll
    for (int n = 0; n < 8; ++n) {
        f32x4 a = {0.f, 0.f, 0.f, 0.f};
        #pragma unroll
        for (int kt = 0; kt < 4; ++kt) {
            bf16x8 wfr = *(const bf16x8*)(w5_s + ((n * 4 + kt) * 64 + l) * 8);
            a = __builtin_amdgcn_mfma_f32_16x16x32_bf16(wfr, pfrag[kt], a, 0, 0, 0);
        }
        acc[n] = a;
    }
    __syncthreads();   // barrier 2: w5/wrbf regions reusable as seg

    bool full = (e0 + EB <= n_edges);
    char* seg = base + wv * 8448;   // 16 rows x 528 B, wave-private

    if (full) {
        #pragma unroll
        for (int n = 0; n < 8; ++n) {
            unsigned int au0 = (n & 1) ? avq[n >> 1].z : avq[n >> 1].x;
            unsigned int au1 = (n & 1) ? avq[n >> 1].w : avq[n >> 1].y;
            unsigned int bu0 = (n & 1) ? bvq[n >> 1].z : bvq[n >> 1].x;
            unsigned int bu1 = (n & 1) ? bvq[n >> 1].w : bvq[n >> 1].y;
            f32x4 o;
            o[0] = swishf(acc[n][0] + bf2f(au0 & 0xffffu) + bf2f(bu0 & 0xffffu));
            o[1] = swishf(acc[n][1] + bf2f(au0 >> 16) + bf2f(bu0 >> 16));
            o[2] = swishf(acc[n][2] + bf2f(au1 & 0xffffu) + bf2f(bu1 & 0xffffu));
            o[3] = swishf(acc[n][3] + bf2f(au1 >> 16) + bf2f(bu1 >> 16));
            *(f32x4*)(seg + er * 528 + n * 64 + g * 16) = o;
        }
        #pragma unroll
        for (int li = 0; li < 4; ++li) {
            #pragma unroll
            for (int eh = 0; eh < 2; ++eh) {
                int e = eh * 8 + (l >> 3);
                int s = l & 7;
                f32x4 v = *(const f32x4*)(seg + e * 528 + li * 128 + s * 16);
                float* dst = out + (size_t)(e0 + wv * 16 + e) * HIDDEN + li * 32 + s * 4;
                __builtin_nontemporal_store(v, (f32x4*)dst);
            }
        }
    } else {
        int ge = e0 + e_loc;
        #pragma unroll
        for (int n = 0; n < 8; ++n) {
            if (ge < n_edges) {
                unsigned int au0 = (n & 1) ? avq[n >> 1].z : avq[n >> 1].x;
                unsigned int au1 = (n & 1) ? avq[n >> 1].w : avq[n >> 1].y;
                unsigned int bu0 = (n & 1) ? bvq[n >> 1].z : bvq[n >> 1].x;
                unsigned int bu1 = (n & 1) ? bvq[n >> 1].w : bvq[n >> 1].y;
                f32x4 o;
                o[0] = swishf(acc[n][0] + bf2f(au0 & 0xffffu) + bf2f(bu0 & 0xffffu));
                o[1] = swishf(acc[n][1] + bf2f(au0 >> 16) + bf2f(bu0 >> 16));
                o[2] = swishf(acc[n][2] + bf2f(au1 & 0xffffu) + bf2f(bu1 & 0xffffu));
                o[3] = swishf(acc[n][3] + bf2f(au1 >> 16) + bf2f(bu1 >> 16));
                *(f32x4*)(out + (size_t)ge * HIDDEN + n * 16 + g * 4) = o;
            }
        }
    }
}

extern "C" void kernel_launch(void* const* d_in, const int* in_sizes, int n_in,
                              void* d_out, int out_size, void* d_ws, size_t ws_size,
                              hipStream_t stream) {
    const int*   x     = (const int*)d_in[0];
    const float* chi   = (const float*)d_in[1];
    const float* rbf   = (const float*)d_in[2];
    const int*   ei    = (const int*)d_in[3];
    const int*   ej    = (const int*)d_in[4];
    const float* emb   = (const float*)d_in[5];
    const float* W_rbf = (const float*)d_in[6];
    const float* b_rbf = (const float*)d_in[7];
    const float* W     = (const float*)d_in[8];
    const float* bvec  = (const float*)d_in[9];
    float* out = (float*)d_out;

    int n_nodes = in_sizes[0];
    int n_edges = in_sizes[3];
    int vocab   = in_sizes[5] / HIDDEN;

    short* Abf = (short*)d_ws;
    short* Bbf = Abf + (size_t)n_nodes * HIDDEN;
    float* T1  = (float*)(Bbf + (size_t)n_nodes * HIDDEN);
    float* T3  = T1 + (size_t)vocab * HIDDEN;
    short* wf  = (short*)(T3 + (size_t)vocab * HIDDEN);
    short* w2f = wf;
    short* w4f = wf + 16384;
    short* w5f = wf + 32768;
    short* wrbf = wf + 49152;

    k_emb_proj<<<vocab, HIDDEN, 0, stream>>>(emb, W, bvec, T1, T3, out + (out_size - 1));
    k_wprep<<<25, 256, 0, stream>>>(W, W_rbf, b_rbf, wf, wrbf);
    k_node<<<(n_nodes + NB - 1) / NB, 256, 0, stream>>>(x, chi, w2f, w4f, T1, T3,
                                                        Abf, Bbf, n_nodes);
    k_edge<<<(n_edges + EB - 1) / EB, 256, 0, stream>>>(rbf, ei, ej, w5f, wrbf,
                                                        Abf, Bbf, out, n_edges);
}

// Round 11
// 209.646 us; speedup vs baseline: 1.0035x; 1.0035x over previous
//
#include <hip/hip_runtime.h>
#include <hip/hip_bf16.h>

#define HIDDEN 128
#define NRAD 6

typedef short bf16x8 __attribute__((ext_vector_type(8)));
typedef float f32x4 __attribute__((ext_vector_type(4)));

__device__ __forceinline__ float swishf(float z) {
    return z / (1.0f + __expf(-z));
}

__device__ __forceinline__ unsigned short f2bf(float f) {
    unsigned int u = __float_as_uint(f);
    unsigned int r = (u + 0x7FFFu + ((u >> 16) & 1u)) >> 16;
    return (unsigned short)r;
}

__device__ __forceinline__ float bf2f(unsigned int s) {
    return __uint_as_float(s << 16);
}

__device__ __forceinline__ unsigned int pk2bf(float x, float y) {
    __hip_bfloat162 h = __float22bfloat162_rn(make_float2(x, y));
    return *reinterpret_cast<unsigned int*>(&h);
}

// ---------------------------------------------------------------------------
// Kernel 1: T1 = emb_table @ W1 + b (bias folded), T3 = emb_table @ W3
// ---------------------------------------------------------------------------
__global__ void k_emb_proj(const float* __restrict__ emb, const float* __restrict__ W,
                           const float* __restrict__ bvec,
                           float* __restrict__ T1, float* __restrict__ T3,
                           float* __restrict__ out_scalar) {
    int v = blockIdx.x;
    int h = threadIdx.x;
    if (v == 0 && h == 0) *out_scalar = 1.0f;
    const float* er = emb + v * HIDDEN;
    float a1 = bvec[h], a3 = 0.f;
    #pragma unroll 4
    for (int k = 0; k < HIDDEN; ++k) {
        float e = er[k];
        a1 += e * W[k * HIDDEN + h];
        a3 += e * W[(256 + k) * HIDDEN + h];
    }
    T1[v * HIDDEN + h] = a1;
    T3[v * HIDDEN + h] = a3;
}

// ---------------------------------------------------------------------------
// Kernel 1b: repack weights into bf16 MFMA fragments.
//  - w2f/w4f: standard k-order W^T A-operand fragments (consumed by k_node).
//  - w5f: pi-PERMUTED k-order: slot s=g*8+j of k-tile kt holds row
//         h = 32*kt + 16*(j>>2) + 4*g + (j&3) (matches phase-1 MFMA output).
//  - wrbf: phase-1 A-operand table (slot 6 = bias, slot 7 = 0).
// ---------------------------------------------------------------------------
__global__ void k_wprep(const float* __restrict__ W,
                        const float* __restrict__ W_rbf, const float* __restrict__ b_rbf,
                        short* __restrict__ wf, short* __restrict__ wrbf) {
    int gid = blockIdx.x * 256 + threadIdx.x;
    if (gid < 4096) {                       // w2f, w4f (standard order)
        int m = gid >> 11;
        int t = gid & 2047;
        int l = t & 63;
        int tile = t >> 6;
        int n = tile >> 2, kt = tile & 3;
        int k0 = kt * 32 + (l >> 4) * 8;
        int col = n * 16 + (l & 15);
        const float* Wm = W + (m == 0 ? 128 : 384) * HIDDEN;
        bf16x8 v;
        #pragma unroll
        for (int j = 0; j < 8; ++j) v[j] = (short)f2bf(Wm[(k0 + j) * HIDDEN + col]);
        *(bf16x8*)(wf + (size_t)gid * 8) = v;
    } else if (gid < 6144) {                // w5f (pi-permuted k order)
        int t = gid - 4096;
        int l = t & 63;
        int tile = t >> 6;
        int n = tile >> 2, kt = tile & 3;
        int g = l >> 4;
        int col = n * 16 + (l & 15);
        const float* W5 = W + 512 * HIDDEN;
        bf16x8 v;
        #pragma unroll
        for (int j = 0; j < 8; ++j) {
            int hk = 32 * kt + 16 * (j >> 2) + 4 * g + (j & 3);
            v[j] = (short)f2bf(W5[hk * HIDDEN + col]);
        }
        *(bf16x8*)(wf + (size_t)gid * 8) = v;
    } else if (gid < 6272) {                // wrbf table (2 KB)
        int t2 = gid - 6144;                // 0..127
        int n = t2 >> 4, e = t2 & 15;
        int hp = n * 16 + e;
        bf16x8 v;
        #pragma unroll
        for (int j = 0; j < 8; ++j) {
            float val = (j < NRAD) ? W_rbf[j * HIDDEN + hp]
                      : (j == 6 ? b_rbf[hp] : 0.f);
            v[j] = (short)f2bf(val);
        }
        *(bf16x8*)(wrbf + (size_t)t2 * 8) = v;
    }
}

// ---------------------------------------------------------------------------
// Kernel 2 (MFMA): A[n] = T1[x[n]] + chi[n]@W2 ; B[n] = T3[x[n]] + chi[n]@W4
// LDS-free; Abf/Bbf stored H-PERMUTED (pos g*32+n*4+j holds h=n*16+g*4+j).
// ---------------------------------------------------------------------------
#define NB 64
__global__ __launch_bounds__(256) void k_node(const int* __restrict__ x,
        const float* __restrict__ chi,
        const short* __restrict__ w2f, const short* __restrict__ w4f,
        const float* __restrict__ T1, const float* __restrict__ T3,
        short* __restrict__ Abf, short* __restrict__ Bbf, int n_nodes) {
    int t = threadIdx.x;
    int l = t & 63;
    int wv = t >> 6;
    int er = l & 15;
    int g = l >> 4;
    int n0 = blockIdx.x * NB;

    int gn = n0 + wv * 16 + er;
    bool live = (gn < n_nodes);
    int ndc = live ? gn : (n_nodes - 1);

    int xv = x[ndc];

    bf16x8 cfrag[4];
    const float* crow = chi + (size_t)ndc * HIDDEN + g * 8;
    #pragma unroll
    for (int kt = 0; kt < 4; ++kt) {
        float4 c0 = *(const float4*)(crow + kt * 32);
        float4 c1 = *(const float4*)(crow + kt * 32 + 4);
        union { bf16x8 v; unsigned int u[4]; } cu;
        cu.u[0] = pk2bf(c0.x, c0.y);
        cu.u[1] = pk2bf(c0.z, c0.w);
        cu.u[2] = pk2bf(c1.x, c1.y);
        cu.u[3] = pk2bf(c1.z, c1.w);
        cfrag[kt] = cu.v;
    }

    int hq = g * 4;
    short* arow = Abf + (size_t)gn * HIDDEN + g * 32;
    short* brow = Bbf + (size_t)gn * HIDDEN + g * 32;

    #pragma unroll
    for (int np = 0; np < 4; ++np) {
        uint4 oa, ob;
        #pragma unroll
        for (int half = 0; half < 2; ++half) {
            int n = 2 * np + half;
            f32x4 aA = {0.f, 0.f, 0.f, 0.f};
            f32x4 aB = {0.f, 0.f, 0.f, 0.f};
            #pragma unroll
            for (int kt = 0; kt < 4; ++kt) {
                bf16x8 w2 = *(const bf16x8*)(w2f + ((size_t)(n * 4 + kt) * 64 + l) * 8);
                bf16x8 w4 = *(const bf16x8*)(w4f + ((size_t)(n * 4 + kt) * 64 + l) * 8);
                aA = __builtin_amdgcn_mfma_f32_16x16x32_bf16(w2, cfrag[kt], aA, 0, 0, 0);
                aB = __builtin_amdgcn_mfma_f32_16x16x32_bf16(w4, cfrag[kt], aB, 0, 0, 0);
            }
            if (live) {
                int h = n * 16 + hq;
                float4 t1 = *(const float4*)(T1 + (size_t)xv * HIDDEN + h);
                float4 t3 = *(const float4*)(T3 + (size_t)xv * HIDDEN + h);
                unsigned int a0 = pk2bf(aA[0] + t1.x, aA[1] + t1.y);
                unsigned int a1 = pk2bf(aA[2] + t1.z, aA[3] + t1.w);
                unsigned int b0 = pk2bf(aB[0] + t3.x, aB[1] + t3.y);
                unsigned int b1 = pk2bf(aB[2] + t3.z, aB[3] + t3.w);
                if (half == 0) { oa.x = a0; oa.y = a1; ob.x = b0; ob.y = b1; }
                else           { oa.z = a0; oa.w = a1; ob.z = b0; ob.w = b1; }
            }
        }
        if (live) {
            *(uint4*)(arow + np * 8) = oa;
            *(uint4*)(brow + np * 8) = ob;
        }
    }
}

// ---------------------------------------------------------------------------
// Kernel 3: 128 edges/block, 8 waves, 512 threads, 2 barriers.
// W5 staged ONCE per 128 edges (halved L2 stage traffic vs EB=64).
// LDS arena (37376 B, 4 blocks/CU = 2048 threads = occupancy cap):
//   [0, 32768)      w5_s (dead after MFMAs)
//   [32768, 34816)  wrbf_s (dead after phase-1)
//   [0, 34816)      after barrier2: 8 per-wave seg buffers (wv*4352, 272-B rows)
//   [34816, 36352)  rbf_b (128 x 6 bf16)
//   [36352, 37376)  i_s, j_s (128 + 128 int)
// Epilogue per-sgi (two 64-h rounds through the wave-private 4352-B seg),
// full 128-B-line NT stores. No barrier between sgi rounds (seg wave-private).
// ---------------------------------------------------------------------------
#define EB 128
__global__ __launch_bounds__(512) void k_edge(const float* __restrict__ rbf,
        const int* __restrict__ ei, const int* __restrict__ ej,
        const short* __restrict__ w5f, const short* __restrict__ wrbf,
        const short* __restrict__ Abf, const short* __restrict__ Bbf,
        float* __restrict__ out, int n_edges) {
    __shared__ uint4 smem4[37376 / 16];
    char* base = (char*)smem4;
    short* w5_s   = (short*)base;
    short* wrbf_s = (short*)(base + 32768);
    unsigned short* rbf_b = (unsigned short*)(base + 34816);
    int*   i_s    = (int*)(base + 36352);
    int*   j_s    = (int*)(base + 36864);

    int e0 = blockIdx.x * EB;
    int t = threadIdx.x;
    int l = t & 63;
    int wv = t >> 6;
    int g = l >> 4;
    int er = l & 15;

    // ---- stage w5 (32 KB), wrbf (2 KB), rbf->bf16, indices ----
    #pragma unroll
    for (int it = 0; it < 4; ++it) {
        int q = t + it * 512;
        ((uint4*)w5_s)[q] = ((const uint4*)w5f)[q];
    }
    if (t < 128) ((uint4*)wrbf_s)[t] = ((const uint4*)wrbf)[t];
    #pragma unroll
    for (int it = 0; it < 2; ++it) {
        int q = t + it * 512;
        if (q < EB * NRAD) {
            int gidx = e0 * NRAD + q;
            rbf_b[q] = (gidx < n_edges * NRAD) ? f2bf(rbf[gidx]) : (unsigned short)0;
        } else if (q < EB * NRAD + EB) {
            int e = q - EB * NRAD;
            int ge = e0 + e;
            i_s[e] = (ge < n_edges) ? ei[ge] : 0;
        } else if (q < EB * NRAD + 2 * EB) {
            int e = q - EB * NRAD - EB;
            int ge = e0 + e;
            j_s[e] = (ge < n_edges) ? ej[ge] : 0;
        }
    }
    __syncthreads();   // barrier 1

    // ---- issue A/B gathers (vmcnt untouched until epilogue) ----
    int e_loc = wv * 16 + er;
    const short* ap = Abf + (size_t)i_s[e_loc] * HIDDEN + g * 32;
    const short* bp = Bbf + (size_t)j_s[e_loc] * HIDDEN + g * 32;
    uint4 avq[4], bvq[4];
    #pragma unroll
    for (int q = 0; q < 4; ++q) {
        avq[q] = *(const uint4*)(ap + q * 8);
        bvq[q] = *(const uint4*)(bp + q * 8);
    }

    // ---- phase-1 via MFMA (K=6 padded to 32; slot6 = 1.0 carries bias) ----
    union { bf16x8 v; unsigned int u[4]; } rbfrag;
    {
        const char* rp = (const char*)rbf_b + e_loc * 12;
        unsigned int q0 = *(const unsigned int*)(rp);
        unsigned int q1 = *(const unsigned int*)(rp + 4);
        unsigned int q2 = *(const unsigned int*)(rp + 8);
        bool g0 = (g == 0);
        rbfrag.u[0] = g0 ? q0 : 0u;
        rbfrag.u[1] = g0 ? q1 : 0u;
        rbfrag.u[2] = g0 ? q2 : 0u;
        rbfrag.u[3] = g0 ? 0x00003F80u : 0u;
    }
    f32x4 accp[8];
    #pragma unroll
    for (int n = 0; n < 8; ++n) {
        bf16x8 wa = *(const bf16x8*)(wrbf_s + (n * 16 + er) * 8);
        f32x4 z = {0.f, 0.f, 0.f, 0.f};
        accp[n] = __builtin_amdgcn_mfma_f32_16x16x32_bf16(wa, rbfrag.v, z, 0, 0, 0);
    }
    unsigned int word0[8], word1[8];
    #pragma unroll
    for (int n = 0; n < 8; ++n) {
        word0[n] = pk2bf(swishf(accp[n][0]), swishf(accp[n][1]));
        word1[n] = pk2bf(swishf(accp[n][2]), swishf(accp[n][3]));
    }
    bf16x8 pfrag[4];
    #pragma unroll
    for (int kt = 0; kt < 4; ++kt) {
        union { bf16x8 v; unsigned int u[4]; } pu;
        pu.u[0] = word0[2 * kt];
        pu.u[1] = word1[2 * kt];
        pu.u[2] = word0[2 * kt + 1];
        pu.u[3] = word1[2 * kt + 1];
        pfrag[kt] = pu.v;
    }

    // ---- main MFMAs: W5 (pi-packed) from LDS ----
    f32x4 acc[8];
    #pragma unroll
    for (int n = 0; n < 8; ++n) {
        f32x4 a = {0.f, 0.f, 0.f, 0.f};
        #pragma unroll
        for (int kt = 0; kt < 4; ++kt) {
            bf16x8 wfr = *(const bf16x8*)(w5_s + ((n * 4 + kt) * 64 + l) * 8);
            a = __builtin_amdgcn_mfma_f32_16x16x32_bf16(wfr, pfrag[kt], a, 0, 0, 0);
        }
        acc[n] = a;
    }
    __syncthreads();   // barrier 2: w5/wrbf regions now the seg arena

    bool full = (e0 + EB <= n_edges);
    char* seg = base + wv * 4352;   // 16 rows x 272 B, wave-private

    if (full) {
        #pragma unroll
        for (int sgi = 0; sgi < 2; ++sgi) {
            #pragma unroll
            for (int nn = 0; nn < 4; ++nn) {
                int n = sgi * 4 + nn;
                unsigned int au0 = (n & 1) ? avq[n >> 1].z : avq[n >> 1].x;
                unsigned int au1 = (n & 1) ? avq[n >> 1].w : avq[n >> 1].y;
                unsigned int bu0 = (n & 1) ? bvq[n >> 1].z : bvq[n >> 1].x;
                unsigned int bu1 = (n & 1) ? bvq[n >> 1].w : bvq[n >> 1].y;
                f32x4 o;
                o[0] = swishf(acc[n][0] + bf2f(au0 & 0xffffu) + bf2f(bu0 & 0xffffu));
                o[1] = swishf(acc[n][1] + bf2f(au0 >> 16) + bf2f(bu0 >> 16));
                o[2] = swishf(acc[n][2] + bf2f(au1 & 0xffffu) + bf2f(bu1 & 0xffffu));
                o[3] = swishf(acc[n][3] + bf2f(au1 >> 16) + bf2f(bu1 >> 16));
                *(f32x4*)(seg + er * 272 + nn * 64 + g * 16) = o;
            }
            // full-line NT stores: 8 rows x 128 B per instruction
            #pragma unroll
            for (int li = 0; li < 2; ++li) {
                #pragma unroll
                for (int eh = 0; eh < 2; ++eh) {
                    int e = eh * 8 + (l >> 3);
                    int s = l & 7;
                    f32x4 v = *(const f32x4*)(seg + e * 272 + li * 128 + s * 16);
                    float* dst = out + (size_t)(e0 + wv * 16 + e) * HIDDEN
                               + sgi * 64 + li * 32 + s * 4;
                    __builtin_nontemporal_store(v, (f32x4*)dst);
                }
            }
        }
    } else {
        int ge = e0 + e_loc;
        #pragma unroll
        for (int n = 0; n < 8; ++n) {
            if (ge < n_edges) {
                unsigned int au0 = (n & 1) ? avq[n >> 1].z : avq[n >> 1].x;
                unsigned int au1 = (n & 1) ? avq[n >> 1].w : avq[n >> 1].y;
                unsigned int bu0 = (n & 1) ? bvq[n >> 1].z : bvq[n >> 1].x;
                unsigned int bu1 = (n & 1) ? bvq[n >> 1].w : bvq[n >> 1].y;
                f32x4 o;
                o[0] = swishf(acc[n][0] + bf2f(au0 & 0xffffu) + bf2f(bu0 & 0xffffu));
                o[1] = swishf(acc[n][1] + bf2f(au0 >> 16) + bf2f(bu0 >> 16));
                o[2] = swishf(acc[n][2] + bf2f(au1 & 0xffffu) + bf2f(bu1 & 0xffffu));
                o[3] = swishf(acc[n][3] + bf2f(au1 >> 16) + bf2f(bu1 >> 16));
                *(f32x4*)(out + (size_t)ge * HIDDEN + n * 16 + g * 4) = o;
            }
        }
    }
}

extern "C" void kernel_launch(void* const* d_in, const int* in_sizes, int n_in,
                              void* d_out, int out_size, void* d_ws, size_t ws_size,
                              hipStream_t stream) {
    const int*   x     = (const int*)d_in[0];
    const float* chi   = (const float*)d_in[1];
    const float* rbf   = (const float*)d_in[2];
    const int*   ei    = (const int*)d_in[3];
    const int*   ej    = (const int*)d_in[4];
    const float* emb   = (const float*)d_in[5];
    const float* W_rbf = (const float*)d_in[6];
    const float* b_rbf = (const float*)d_in[7];
    const float* W     = (const float*)d_in[8];
    const float* bvec  = (const float*)d_in[9];
    float* out = (float*)d_out;

    int n_nodes = in_sizes[0];
    int n_edges = in_sizes[3];
    int vocab   = in_sizes[5] / HIDDEN;

    short* Abf = (short*)d_ws;
    short* Bbf = Abf + (size_t)n_nodes * HIDDEN;
    float* T1  = (float*)(Bbf + (size_t)n_nodes * HIDDEN);
    float* T3  = T1 + (size_t)vocab * HIDDEN;
    short* wf  = (short*)(T3 + (size_t)vocab * HIDDEN);
    short* w2f = wf;
    short* w4f = wf + 16384;
    short* w5f = wf + 32768;
    short* wrbf = wf + 49152;

    k_emb_proj<<<vocab, HIDDEN, 0, stream>>>(emb, W, bvec, T1, T3, out + (out_size - 1));
    k_wprep<<<25, 256, 0, stream>>>(W, W_rbf, b_rbf, wf, wrbf);
    k_node<<<(n_nodes + NB - 1) / NB, 256, 0, stream>>>(x, chi, w2f, w4f, T1, T3,
                                                        Abf, Bbf, n_nodes);
    k_edge<<<(n_edges + EB - 1) / EB, 512, 0, stream>>>(rbf, ei, ej, w5f, wrbf,
                                                        Abf, Bbf, out, n_edges);
}

// Round 12
// 209.031 us; speedup vs baseline: 1.0065x; 1.0029x over previous
//
#include <hip/hip_runtime.h>
#include <hip/hip_bf16.h>

#define HIDDEN 128
#define NRAD 6

typedef short bf16x8 __attribute__((ext_vector_type(8)));
typedef float f32x4 __attribute__((ext_vector_type(4)));

__device__ __forceinline__ float swishf(float z) {
    return z / (1.0f + __expf(-z));
}

__device__ __forceinline__ unsigned short f2bf(float f) {
    unsigned int u = __float_as_uint(f);
    unsigned int r = (u + 0x7FFFu + ((u >> 16) & 1u)) >> 16;
    return (unsigned short)r;
}

__device__ __forceinline__ float bf2f(unsigned int s) {
    return __uint_as_float(s << 16);
}

__device__ __forceinline__ unsigned int pk2bf(float x, float y) {
    __hip_bfloat162 h = __float22bfloat162_rn(make_float2(x, y));
    return *reinterpret_cast<unsigned int*>(&h);
}

// ---------------------------------------------------------------------------
// Kernel 1: T1 = emb_table @ W1 + b (bias folded), T3 = emb_table @ W3
// ---------------------------------------------------------------------------
__global__ void k_emb_proj(const float* __restrict__ emb, const float* __restrict__ W,
                           const float* __restrict__ bvec,
                           float* __restrict__ T1, float* __restrict__ T3,
                           float* __restrict__ out_scalar) {
    int v = blockIdx.x;
    int h = threadIdx.x;
    if (v == 0 && h == 0) *out_scalar = 1.0f;
    const float* er = emb + v * HIDDEN;
    float a1 = bvec[h], a3 = 0.f;
    #pragma unroll 4
    for (int k = 0; k < HIDDEN; ++k) {
        float e = er[k];
        a1 += e * W[k * HIDDEN + h];
        a3 += e * W[(256 + k) * HIDDEN + h];
    }
    T1[v * HIDDEN + h] = a1;
    T3[v * HIDDEN + h] = a3;
}

// ---------------------------------------------------------------------------
// Kernel 1b: repack weights into bf16 MFMA fragments.
//  - w2f/w4f: standard k-order W^T A-operand fragments (consumed by k_node).
//  - w5f: pi-PERMUTED k-order: slot s=g*8+j of k-tile kt holds row
//         h = 32*kt + 16*(j>>2) + 4*g + (j&3) (matches phase-1 MFMA output).
//  - wrbf: phase-1 A-operand table (slot 6 = bias, slot 7 = 0).
// ---------------------------------------------------------------------------
__global__ void k_wprep(const float* __restrict__ W,
                        const float* __restrict__ W_rbf, const float* __restrict__ b_rbf,
                        short* __restrict__ wf, short* __restrict__ wrbf) {
    int gid = blockIdx.x * 256 + threadIdx.x;
    if (gid < 4096) {                       // w2f, w4f (standard order)
        int m = gid >> 11;
        int t = gid & 2047;
        int l = t & 63;
        int tile = t >> 6;
        int n = tile >> 2, kt = tile & 3;
        int k0 = kt * 32 + (l >> 4) * 8;
        int col = n * 16 + (l & 15);
        const float* Wm = W + (m == 0 ? 128 : 384) * HIDDEN;
        bf16x8 v;
        #pragma unroll
        for (int j = 0; j < 8; ++j) v[j] = (short)f2bf(Wm[(k0 + j) * HIDDEN + col]);
        *(bf16x8*)(wf + (size_t)gid * 8) = v;
    } else if (gid < 6144) {                // w5f (pi-permuted k order)
        int t = gid - 4096;
        int l = t & 63;
        int tile = t >> 6;
        int n = tile >> 2, kt = tile & 3;
        int g = l >> 4;
        int col = n * 16 + (l & 15);
        const float* W5 = W + 512 * HIDDEN;
        bf16x8 v;
        #pragma unroll
        for (int j = 0; j < 8; ++j) {
            int hk = 32 * kt + 16 * (j >> 2) + 4 * g + (j & 3);
            v[j] = (short)f2bf(W5[hk * HIDDEN + col]);
        }
        *(bf16x8*)(wf + (size_t)gid * 8) = v;
    } else if (gid < 6272) {                // wrbf table (2 KB)
        int t2 = gid - 6144;                // 0..127
        int n = t2 >> 4, e = t2 & 15;
        int hp = n * 16 + e;
        bf16x8 v;
        #pragma unroll
        for (int j = 0; j < 8; ++j) {
            float val = (j < NRAD) ? W_rbf[j * HIDDEN + hp]
                      : (j == 6 ? b_rbf[hp] : 0.f);
            v[j] = (short)f2bf(val);
        }
        *(bf16x8*)(wrbf + (size_t)t2 * 8) = v;
    }
}

// ---------------------------------------------------------------------------
// Kernel 2 (MFMA): A[n] = T1[x[n]] + chi[n]@W2 ; B[n] = T3[x[n]] + chi[n]@W4
// LDS-free; Abf/Bbf stored H-PERMUTED (pos g*32+n*4+j holds h=n*16+g*4+j).
// ---------------------------------------------------------------------------
#define NB 64
__global__ __launch_bounds__(256) void k_node(const int* __restrict__ x,
        const float* __restrict__ chi,
        const short* __restrict__ w2f, const short* __restrict__ w4f,
        const float* __restrict__ T1, const float* __restrict__ T3,
        short* __restrict__ Abf, short* __restrict__ Bbf, int n_nodes) {
    int t = threadIdx.x;
    int l = t & 63;
    int wv = t >> 6;
    int er = l & 15;
    int g = l >> 4;
    int n0 = blockIdx.x * NB;

    int gn = n0 + wv * 16 + er;
    bool live = (gn < n_nodes);
    int ndc = live ? gn : (n_nodes - 1);

    int xv = x[ndc];

    bf16x8 cfrag[4];
    const float* crow = chi + (size_t)ndc * HIDDEN + g * 8;
    #pragma unroll
    for (int kt = 0; kt < 4; ++kt) {
        float4 c0 = *(const float4*)(crow + kt * 32);
        float4 c1 = *(const float4*)(crow + kt * 32 + 4);
        union { bf16x8 v; unsigned int u[4]; } cu;
        cu.u[0] = pk2bf(c0.x, c0.y);
        cu.u[1] = pk2bf(c0.z, c0.w);
        cu.u[2] = pk2bf(c1.x, c1.y);
        cu.u[3] = pk2bf(c1.z, c1.w);
        cfrag[kt] = cu.v;
    }

    int hq = g * 4;
    short* arow = Abf + (size_t)gn * HIDDEN + g * 32;
    short* brow = Bbf + (size_t)gn * HIDDEN + g * 32;

    #pragma unroll
    for (int np = 0; np < 4; ++np) {
        uint4 oa, ob;
        #pragma unroll
        for (int half = 0; half < 2; ++half) {
            int n = 2 * np + half;
            f32x4 aA = {0.f, 0.f, 0.f, 0.f};
            f32x4 aB = {0.f, 0.f, 0.f, 0.f};
            #pragma unroll
            for (int kt = 0; kt < 4; ++kt) {
                bf16x8 w2 = *(const bf16x8*)(w2f + ((size_t)(n * 4 + kt) * 64 + l) * 8);
                bf16x8 w4 = *(const bf16x8*)(w4f + ((size_t)(n * 4 + kt) * 64 + l) * 8);
                aA = __builtin_amdgcn_mfma_f32_16x16x32_bf16(w2, cfrag[kt], aA, 0, 0, 0);
                aB = __builtin_amdgcn_mfma_f32_16x16x32_bf16(w4, cfrag[kt], aB, 0, 0, 0);
            }
            if (live) {
                int h = n * 16 + hq;
                float4 t1 = *(const float4*)(T1 + (size_t)xv * HIDDEN + h);
                float4 t3 = *(const float4*)(T3 + (size_t)xv * HIDDEN + h);
                unsigned int a0 = pk2bf(aA[0] + t1.x, aA[1] + t1.y);
                unsigned int a1 = pk2bf(aA[2] + t1.z, aA[3] + t1.w);
                unsigned int b0 = pk2bf(aB[0] + t3.x, aB[1] + t3.y);
                unsigned int b1 = pk2bf(aB[2] + t3.z, aB[3] + t3.w);
                if (half == 0) { oa.x = a0; oa.y = a1; ob.x = b0; ob.y = b1; }
                else           { oa.z = a0; oa.w = a1; ob.z = b0; ob.w = b1; }
            }
        }
        if (live) {
            *(uint4*)(arow + np * 8) = oa;
            *(uint4*)(brow + np * 8) = ob;
        }
    }
}

// ---------------------------------------------------------------------------
// Kernel 3: 128 edges/block, 8 waves, 512 threads, 2 barriers.
// Gather-latency fix: i/j indices and A/B gathers issued at KERNEL ENTRY
// (direct global loads, no LDS round-trip); the implicit vmcnt(0) at
// barrier1 forces them complete while overlapped with the 32 KB W5 staging.
// rbf also loaded directly per-lane (3 x float2, 8-B aligned).
// LDS arena (34816 B, 4 blocks/CU):
//   [0, 32768)   w5_s (dead after MFMAs)
//   [32768, 34816) wrbf_s (dead after phase-1)
//   [0, 34816)   after barrier2: 8 per-wave seg buffers (wv*4352, 272-B rows)
// ---------------------------------------------------------------------------
#define EB 128
__global__ __launch_bounds__(512) void k_edge(const float* __restrict__ rbf,
        const int* __restrict__ ei, const int* __restrict__ ej,
        const short* __restrict__ w5f, const short* __restrict__ wrbf,
        const short* __restrict__ Abf, const short* __restrict__ Bbf,
        float* __restrict__ out, int n_edges) {
    __shared__ uint4 smem4[34816 / 16];
    char* base = (char*)smem4;
    short* w5_s   = (short*)base;
    short* wrbf_s = (short*)(base + 32768);

    int e0 = blockIdx.x * EB;
    int t = threadIdx.x;
    int l = t & 63;
    int wv = t >> 6;
    int g = l >> 4;
    int er = l & 15;

    int e_loc = wv * 16 + er;
    int ge = e0 + e_loc;
    int gec = min(ge, n_edges - 1);

    // ---- indices + A/B gathers issued FIRST (full staging window to land) ----
    int iv = ei[gec];
    int jv = ej[gec];
    const short* ap = Abf + (size_t)iv * HIDDEN + g * 32;
    const short* bp = Bbf + (size_t)jv * HIDDEN + g * 32;
    uint4 avq[4], bvq[4];
    #pragma unroll
    for (int q = 0; q < 4; ++q) {
        avq[q] = *(const uint4*)(ap + q * 8);
        bvq[q] = *(const uint4*)(bp + q * 8);
    }
    // rbf direct load (24*e bytes -> always 8-B aligned)
    float2 r01 = *(const float2*)(rbf + (size_t)gec * NRAD);
    float2 r23 = *(const float2*)(rbf + (size_t)gec * NRAD + 2);
    float2 r45 = *(const float2*)(rbf + (size_t)gec * NRAD + 4);

    // ---- stage w5 (32 KB) + wrbf (2 KB) ----
    #pragma unroll
    for (int it = 0; it < 4; ++it) {
        int q = t + it * 512;
        ((uint4*)w5_s)[q] = ((const uint4*)w5f)[q];
    }
    if (t < 128) ((uint4*)wrbf_s)[t] = ((const uint4*)wrbf)[t];
    __syncthreads();   // barrier 1: drains staging AND gathers (overlapped)

    // ---- phase-1 via MFMA (K=6 padded to 32; slot6 = 1.0 carries bias) ----
    union { bf16x8 v; unsigned int u[4]; } rbfrag;
    {
        bool g0 = (g == 0);
        rbfrag.u[0] = g0 ? pk2bf(r01.x, r01.y) : 0u;
        rbfrag.u[1] = g0 ? pk2bf(r23.x, r23.y) : 0u;
        rbfrag.u[2] = g0 ? pk2bf(r45.x, r45.y) : 0u;
        rbfrag.u[3] = g0 ? 0x00003F80u : 0u;
    }
    f32x4 accp[8];
    #pragma unroll
    for (int n = 0; n < 8; ++n) {
        bf16x8 wa = *(const bf16x8*)(wrbf_s + (n * 16 + er) * 8);
        f32x4 z = {0.f, 0.f, 0.f, 0.f};
        accp[n] = __builtin_amdgcn_mfma_f32_16x16x32_bf16(wa, rbfrag.v, z, 0, 0, 0);
    }
    unsigned int word0[8], word1[8];
    #pragma unroll
    for (int n = 0; n < 8; ++n) {
        word0[n] = pk2bf(swishf(accp[n][0]), swishf(accp[n][1]));
        word1[n] = pk2bf(swishf(accp[n][2]), swishf(accp[n][3]));
    }
    bf16x8 pfrag[4];
    #pragma unroll
    for (int kt = 0; kt < 4; ++kt) {
        union { bf16x8 v; unsigned int u[4]; } pu;
        pu.u[0] = word0[2 * kt];
        pu.u[1] = word1[2 * kt];
        pu.u[2] = word0[2 * kt + 1];
        pu.u[3] = word1[2 * kt + 1];
        pfrag[kt] = pu.v;
    }

    // ---- main MFMAs: W5 (pi-packed) from LDS ----
    f32x4 acc[8];
    #pragma unroll
    for (int n = 0; n < 8; ++n) {
        f32x4 a = {0.f, 0.f, 0.f, 0.f};
        #pragma unroll
        for (int kt = 0; kt < 4; ++kt) {
            bf16x8 wfr = *(const bf16x8*)(w5_s + ((n * 4 + kt) * 64 + l) * 8);
            a = __builtin_amdgcn_mfma_f32_16x16x32_bf16(wfr, pfrag[kt], a, 0, 0, 0);
        }
        acc[n] = a;
    }
    __syncthreads();   // barrier 2: w5/wrbf regions become the seg arena

    bool full = (e0 + EB <= n_edges);
    char* seg = base + wv * 4352;   // 16 rows x 272 B, wave-private

    if (full) {
        #pragma unroll
        for (int sgi = 0; sgi < 2; ++sgi) {
            #pragma unroll
            for (int nn = 0; nn < 4; ++nn) {
                int n = sgi * 4 + nn;
                unsigned int au0 = (n & 1) ? avq[n >> 1].z : avq[n >> 1].x;
                unsigned int au1 = (n & 1) ? avq[n >> 1].w : avq[n >> 1].y;
                unsigned int bu0 = (n & 1) ? bvq[n >> 1].z : bvq[n >> 1].x;
                unsigned int bu1 = (n & 1) ? bvq[n >> 1].w : bvq[n >> 1].y;
                f32x4 o;
                o[0] = swishf(acc[n][0] + bf2f(au0 & 0xffffu) + bf2f(bu0 & 0xffffu));
                o[1] = swishf(acc[n][1] + bf2f(au0 >> 16) + bf2f(bu0 >> 16));
                o[2] = swishf(acc[n][2] + bf2f(au1 & 0xffffu) + bf2f(bu1 & 0xffffu));
                o[3] = swishf(acc[n][3] + bf2f(au1 >> 16) + bf2f(bu1 >> 16));
                *(f32x4*)(seg + er * 272 + nn * 64 + g * 16) = o;
            }
            #pragma unroll
            for (int li = 0; li < 2; ++li) {
                #pragma unroll
                for (int eh = 0; eh < 2; ++eh) {
                    int e = eh * 8 + (l >> 3);
                    int s = l & 7;
                    f32x4 v = *(const f32x4*)(seg + e * 272 + li * 128 + s * 16);
                    float* dst = out + (size_t)(e0 + wv * 16 + e) * HIDDEN
                               + sgi * 64 + li * 32 + s * 4;
                    __builtin_nontemporal_store(v, (f32x4*)dst);
                }
            }
        }
    } else {
        #pragma unroll
        for (int n = 0; n < 8; ++n) {
            if (ge < n_edges) {
                unsigned int au0 = (n & 1) ? avq[n >> 1].z : avq[n >> 1].x;
                unsigned int au1 = (n & 1) ? avq[n >> 1].w : avq[n >> 1].y;
                unsigned int bu0 = (n & 1) ? bvq[n >> 1].z : bvq[n >> 1].x;
                unsigned int bu1 = (n & 1) ? bvq[n >> 1].w : bvq[n >> 1].y;
                f32x4 o;
                o[0] = swishf(acc[n][0] + bf2f(au0 & 0xffffu) + bf2f(bu0 & 0xffffu));
                o[1] = swishf(acc[n][1] + bf2f(au0 >> 16) + bf2f(bu0 >> 16));
                o[2] = swishf(acc[n][2] + bf2f(au1 & 0xffffu) + bf2f(bu1 & 0xffffu));
                o[3] = swishf(acc[n][3] + bf2f(au1 >> 16) + bf2f(bu1 >> 16));
                *(f32x4*)(out + (size_t)ge * HIDDEN + n * 16 + g * 4) = o;
            }
        }
    }
}

extern "C" void kernel_launch(void* const* d_in, const int* in_sizes, int n_in,
                              void* d_out, int out_size, void* d_ws, size_t ws_size,
                              hipStream_t stream) {
    const int*   x     = (const int*)d_in[0];
    const float* chi   = (const float*)d_in[1];
    const float* rbf   = (const float*)d_in[2];
    const int*   ei    = (const int*)d_in[3];
    const int*   ej    = (const int*)d_in[4];
    const float* emb   = (const float*)d_in[5];
    const float* W_rbf = (const float*)d_in[6];
    const float* b_rbf = (const float*)d_in[7];
    const float* W     = (const float*)d_in[8];
    const float* bvec  = (const float*)d_in[9];
    float* out = (float*)d_out;

    int n_nodes = in_sizes[0];
    int n_edges = in_sizes[3];
    int vocab   = in_sizes[5] / HIDDEN;

    short* Abf = (short*)d_ws;
    short* Bbf = Abf + (size_t)n_nodes * HIDDEN;
    float* T1  = (float*)(Bbf + (size_t)n_nodes * HIDDEN);
    float* T3  = T1 + (size_t)vocab * HIDDEN;
    short* wf  = (short*)(T3 + (size_t)vocab * HIDDEN);
    short* w2f = wf;
    short* w4f = wf + 16384;
    short* w5f = wf + 32768;
    short* wrbf = wf + 49152;

    k_emb_proj<<<vocab, HIDDEN, 0, stream>>>(emb, W, bvec, T1, T3, out + (out_size - 1));
    k_wprep<<<25, 256, 0, stream>>>(W, W_rbf, b_rbf, wf, wrbf);
    k_node<<<(n_nodes + NB - 1) / NB, 256, 0, stream>>>(x, chi, w2f, w4f, T1, T3,
                                                        Abf, Bbf, n_nodes);
    k_edge<<<(n_edges + EB - 1) / EB, 512, 0, stream>>>(rbf, ei, ej, w5f, wrbf,
                                                        Abf, Bbf, out, n_edges);
}